// Round 11
// baseline (74.800 us; speedup 1.0000x reference)
//
#include <hip/hip_runtime.h>

#define T_STEPS 100
#define BATCH 256
#define NIN 784
#define N0 64
#define N1 64
#define N2 10
#define CHUNK (BATCH*N0 + BATCH*N1 + BATCH*N2)   // 35328
#define KPAD 800
#define WPLANE (N0*KPAD)                         // 51200 shorts per split plane
#define I0ELEMS (25600*64)

typedef __attribute__((ext_vector_type(8))) short short8;
typedef __attribute__((ext_vector_type(4))) float f32x4;

__device__ inline short bf16_rne(float x) {
  unsigned u = __float_as_uint(x);
  unsigned h = (u + 0x7FFFu + ((u >> 16) & 1u)) >> 16;
  return (short)h;
}
__device__ inline float bf16_val(short h) {
  return __uint_as_float(((unsigned)(unsigned short)h) << 16);
}

// ---------------------------------------------------------------------------
// Kernel 0: split W0 (f32 [64][784]) into 3 bf16 planes [64][800] (zero-pad).
// ---------------------------------------------------------------------------
__global__ __launch_bounds__(256) void prep_w0(
    const float* __restrict__ W0, short* __restrict__ W0s) {
  int idx = blockIdx.x * 256 + threadIdx.x;      // 0..51199
  int col = idx / KPAD, k = idx - col * KPAD;
  float w = (k < NIN) ? W0[col * NIN + k] : 0.0f;
  short h0 = bf16_rne(w);
  float r1 = w - bf16_val(h0);
  short h1 = bf16_rne(r1);
  float r2 = r1 - bf16_val(h1);
  short h2 = bf16_rne(r2);
  W0s[idx]              = h0;
  W0s[WPLANE + idx]     = h1;
  W0s[2 * WPLANE + idx] = h2;
}

// ---------------------------------------------------------------------------
// Kernel 1: I0T = X @ W0^T + b0 via bf16x3 MFMA, fragments direct from global.
// R11: block = 16 rows x 64 cols, 4 waves = same 4 k-ranges as R10
// ({192,192,192,224-pad}) -> grid 1600, 6400 waves (2x R10) for TLP latency
// hiding. All FP chains (chunk order, product order, reduce order) are
// BIT-IDENTICAL to R10's passing output.
// ---------------------------------------------------------------------------
__global__ __launch_bounds__(256) void gemm0_kernel(
    const float* __restrict__ X, const short* __restrict__ W0s,
    const float* __restrict__ b0, float* __restrict__ I0T) {
  __shared__ float red[4][16][68];               // 17.4 KB wave-partials

  const int tid = threadIdx.x;
  const int r0  = blockIdx.x * 16;
  const int wid = tid >> 6;                      // wave 0..3 = k-split
  const int l   = tid & 63;
  const int lr  = l & 15;                        // frag row/col lane
  const int lk  = l >> 4;                        // frag k-octet lane

  const int kbeg = wid * 192;
  const int ccnt = (wid < 3) ? 6 : 7;            // last: 208 real k + 16 pad

  f32x4 acc[4];                                  // [col-tile]
#pragma unroll
  for (int ct = 0; ct < 4; ++ct) acc[ct] = f32x4{0.f, 0.f, 0.f, 0.f};

  const float*  xr0 = X + (size_t)(r0 + lr) * NIN;
  const short8* wp  = (const short8*)W0s;        // 100 short8 per row

  // ---- prologue: A-load chunk 0
  float4 cxa, cxb;
  {
    const int k0 = kbeg + lk * 8;
    if (k0 < NIN) {
      cxa = *(const float4*)(xr0 + k0);
      cxb = *(const float4*)(xr0 + k0 + 4);
    } else {
      cxa = cxb = float4{0.f, 0.f, 0.f, 0.f};
    }
  }

  for (int c = 0; c < ccnt; ++c) {
    const int kb = kbeg + c * 32;
    const bool more = (c + 1 < ccnt);

    // ---- issue next chunk's A-loads (HBM latency hides under this chunk)
    float4 nxa, nxb;
    if (more) {
      const int k0n = kb + 32 + lk * 8;
      if (k0n < NIN) {
        nxa = *(const float4*)(xr0 + k0n);
        nxb = *(const float4*)(xr0 + k0n + 4);
      } else {
        nxa = nxb = float4{0.f, 0.f, 0.f, 0.f};
      }
    }

    // ---- batch-issue this chunk's 12 B-loads (L2-resident)
    const int kof = kb / 8 + lk;
    short8 cb[4][3];
#pragma unroll
    for (int ct = 0; ct < 4; ++ct) {
      const size_t col = (size_t)(ct * 16 + lr);
      cb[ct][0] = wp[        col * 100 + kof];
      cb[ct][1] = wp[ 6400 + col * 100 + kof];
      cb[ct][2] = wp[12800 + col * 100 + kof];
    }

    // ---- convert this chunk's A to bf16x3 fragments (overlaps B latency)
    short8 a0[3];
    {
      float xs[8] = {cxa.x, cxa.y, cxa.z, cxa.w, cxb.x, cxb.y, cxb.z, cxb.w};
#pragma unroll
      for (int e = 0; e < 8; ++e) {
        float x  = xs[e];
        short h0 = bf16_rne(x);   float rr1 = x - bf16_val(h0);
        short h1 = bf16_rne(rr1); float rr2 = rr1 - bf16_val(h1);
        a0[0][e] = h0; a0[1][e] = h1; a0[2][e] = bf16_rne(rr2);
      }
    }

    // ---- MFMA: 4 col-tiles x 6 products (R10 order)
#pragma unroll
    for (int ct = 0; ct < 4; ++ct) {
      f32x4 a = acc[ct];
      a = __builtin_amdgcn_mfma_f32_16x16x32_bf16(a0[2], cb[ct][0], a, 0, 0, 0);
      a = __builtin_amdgcn_mfma_f32_16x16x32_bf16(a0[0], cb[ct][2], a, 0, 0, 0);
      a = __builtin_amdgcn_mfma_f32_16x16x32_bf16(a0[1], cb[ct][1], a, 0, 0, 0);
      a = __builtin_amdgcn_mfma_f32_16x16x32_bf16(a0[1], cb[ct][0], a, 0, 0, 0);
      a = __builtin_amdgcn_mfma_f32_16x16x32_bf16(a0[0], cb[ct][1], a, 0, 0, 0);
      a = __builtin_amdgcn_mfma_f32_16x16x32_bf16(a0[0], cb[ct][0], a, 0, 0, 0);
      acc[ct] = a;
    }

    // ---- rotate prefetched A into current
    if (more) { cxa = nxa; cxb = nxb; }
  }

  // ---- epilogue: wave-partials -> LDS  (C/D: col=l&15, row=(l>>4)*4+r)
#pragma unroll
  for (int ct = 0; ct < 4; ++ct)
#pragma unroll
    for (int r = 0; r < 4; ++r)
      red[wid][lk * 4 + r][ct * 16 + lr] = acc[ct][r];
  __syncthreads();

  // ---- reduce 4 partials + bias (R10 order), write b-major I0T
  const int t0  = r0 >> 8;
  const int bb0 = r0 & 255;
  {
    int row = tid >> 4, q = tid & 15;            // 256 threads = 16 rows x 16 f4
    float4 v  = *(const float4*)&red[0][row][q * 4];
    float4 u1 = *(const float4*)&red[1][row][q * 4];
    float4 u2 = *(const float4*)&red[2][row][q * 4];
    float4 u3 = *(const float4*)&red[3][row][q * 4];
    v.x += u1.x; v.y += u1.y; v.z += u1.z; v.w += u1.w;
    v.x += u2.x; v.y += u2.y; v.z += u2.z; v.w += u2.w;
    v.x += u3.x; v.y += u3.y; v.z += u3.z; v.w += u3.w;
    float4 bv = ((const float4*)b0)[q];
    v.x += bv.x; v.y += bv.y; v.z += bv.z; v.w += bv.w;
    ((float4*)I0T)[((size_t)(bb0 + row) * T_STEPS + t0) * 16 + q] = v;
  }
}

// ---------------------------------------------------------------------------
// Kernel 2: one block per batch element (unchanged).
// ---------------------------------------------------------------------------
__global__ __launch_bounds__(256) void fused_kernel(
    const float* __restrict__ I0T,
    const float* __restrict__ W1, const float* __restrict__ b1,
    const float* __restrict__ W2, const float* __restrict__ b2,
    float* __restrict__ out) {
  __shared__ float bufA[112][68];
  __shared__ float sW1t[64][68];
  __shared__ float sW2[N2][68];
  __shared__ float sI2[T_STEPS][N2];

  const int b   = blockIdx.x;
  const int tid = threadIdx.x;
  const int j   = tid & 63;
  const int tq  = tid >> 6;
  float* outSpk = out;
  float* laySpk = out + T_STEPS * BATCH * N2;

  {
    const float4* src = (const float4*)I0T + (size_t)b * (T_STEPS * 16);
    for (int idx = tid; idx < T_STEPS * 16; idx += 256) {
      float4 v = src[idx];
      int t = idx >> 4, j4 = idx & 15;
      *(float4*)&bufA[t][j4 * 4] = v;
    }
  }
  __syncthreads();

  if (tq == 0) {
    float v = 0.0f;
#pragma unroll
    for (int g = 0; g < 4; ++g) {
      float ic[25];
#pragma unroll
      for (int i = 0; i < 25; ++i) ic[i] = bufA[g * 25 + i][j];
#pragma unroll
      for (int i = 0; i < 25; ++i) {
        v = v + 0.05f * ((0.0f - v) + ic[i]);
        float z = (v > 1.0f) ? 1.0f : 0.0f;
        v -= z;
        ic[i] = z;
      }
#pragma unroll
      for (int i = 0; i < 25; ++i) bufA[g * 25 + i][j] = ic[i];
    }
  } else {
    for (int idx = tid - 64; idx < 64 * 16; idx += 192) {
      int i = idx >> 4, jv = idx & 15;
      float4 wv = *(const float4*)(W1 + (size_t)i * 64 + jv * 4);
      sW1t[jv * 4 + 0][i] = wv.x;
      sW1t[jv * 4 + 1][i] = wv.y;
      sW1t[jv * 4 + 2][i] = wv.z;
      sW1t[jv * 4 + 3][i] = wv.w;
    }
    for (int idx = tid - 64; idx < N2 * 16; idx += 192) {
      int o = idx >> 4, jv = idx & 15;
      *(float4*)&sW2[o][jv * 4] = *(const float4*)(W2 + (size_t)o * 64 + jv * 4);
    }
  }
  __syncthreads();

  for (int idx = tid; idx < T_STEPS * 16; idx += 256) {
    int t = idx >> 4, jv = idx & 15;
    *(float4*)(laySpk + (size_t)t * CHUNK + b * 64 + jv * 4) =
        *(const float4*)&bufA[t][jv * 4];
  }

  const int iq = tid & 15;
  const int ts = tid >> 4;
  float g1[4][7];
  {
    float4 bias = *(const float4*)(b1 + iq * 4);
#pragma unroll
    for (int tt = 0; tt < 7; ++tt) {
      g1[0][tt] = bias.x; g1[1][tt] = bias.y; g1[2][tt] = bias.z; g1[3][tt] = bias.w;
    }
#pragma unroll
    for (int jq = 0; jq < 16; ++jq) {
      float4 z4[7];
#pragma unroll
      for (int tt = 0; tt < 7; ++tt)
        z4[tt] = *(const float4*)&bufA[ts * 7 + tt][jq * 4];
      float4 w4[4];
#pragma unroll
      for (int e = 0; e < 4; ++e)
        w4[e] = *(const float4*)&sW1t[jq * 4 + e][iq * 4];
#pragma unroll
      for (int e = 0; e < 4; ++e) {
#pragma unroll
        for (int tt = 0; tt < 7; ++tt) {
          float zv = ((const float*)&z4[tt])[e];
          g1[0][tt] = fmaf(zv, w4[e].x, g1[0][tt]);
          g1[1][tt] = fmaf(zv, w4[e].y, g1[1][tt]);
          g1[2][tt] = fmaf(zv, w4[e].z, g1[2][tt]);
          g1[3][tt] = fmaf(zv, w4[e].w, g1[3][tt]);
        }
      }
    }
  }
  __syncthreads();
#pragma unroll
  for (int tt = 0; tt < 7; ++tt) {
    float4 o = {g1[0][tt], g1[1][tt], g1[2][tt], g1[3][tt]};
    *(float4*)&bufA[ts * 7 + tt][iq * 4] = o;
  }
  __syncthreads();

  if (tq == 0) {
    float v = 0.0f;
#pragma unroll
    for (int g = 0; g < 4; ++g) {
      float ic[25];
#pragma unroll
      for (int i = 0; i < 25; ++i) ic[i] = bufA[g * 25 + i][j];
#pragma unroll
      for (int i = 0; i < 25; ++i) {
        v = v + 0.05f * ((0.0f - v) + ic[i]);
        float z = (v > 1.0f) ? 1.0f : 0.0f;
        v -= z;
        ic[i] = z;
      }
#pragma unroll
      for (int i = 0; i < 25; ++i) bufA[g * 25 + i][j] = ic[i];
    }
  }
  __syncthreads();

  for (int idx = tid; idx < T_STEPS * 16; idx += 256) {
    int t = idx >> 4, jv = idx & 15;
    *(float4*)(laySpk + (size_t)t * CHUNK + BATCH * N0 + b * 64 + jv * 4) =
        *(const float4*)&bufA[t][jv * 4];
  }

  for (int idx = tid; idx < T_STEPS * N2; idx += 256) {
    int t = idx / N2, o = idx % N2;
    float a = b2[o];
#pragma unroll
    for (int jq = 0; jq < 16; ++jq) {
      float4 z = *(const float4*)&bufA[t][jq * 4];
      float4 wv = *(const float4*)&sW2[o][jq * 4];
      a += z.x * wv.x;
      a += z.y * wv.y;
      a += z.z * wv.z;
      a += z.w * wv.w;
    }
    sI2[t][o] = a;
  }
  __syncthreads();

  if (tid < N2) {
    float v = 0.0f;
#pragma unroll
    for (int g = 0; g < 4; ++g) {
      float ic[25];
#pragma unroll
      for (int i = 0; i < 25; ++i) ic[i] = sI2[g * 25 + i][tid];
#pragma unroll
      for (int i = 0; i < 25; ++i) {
        v = v + 0.05f * ((0.0f - v) + ic[i]);
        float z = (v > 1.0f) ? 1.0f : 0.0f;
        v -= z;
        ic[i] = z;
      }
#pragma unroll
      for (int i = 0; i < 25; ++i) sI2[g * 25 + i][tid] = ic[i];
    }
  }
  __syncthreads();

  for (int idx = tid; idx < T_STEPS * N2; idx += 256) {
    int t = idx / N2, o = idx % N2;
    float z = sI2[t][o];
    outSpk[(size_t)t * (BATCH * N2) + b * N2 + o] = z;
    laySpk[(size_t)t * CHUNK + BATCH * (N0 + N1) + b * N2 + o] = z;
  }
}

extern "C" void kernel_launch(void* const* d_in, const int* in_sizes, int n_in,
                              void* d_out, int out_size, void* d_ws, size_t ws_size,
                              hipStream_t stream) {
  const float* inp = (const float*)d_in[0];
  const float* W0  = (const float*)d_in[1];
  const float* b0  = (const float*)d_in[2];
  const float* W1  = (const float*)d_in[3];
  const float* b1  = (const float*)d_in[4];
  const float* W2  = (const float*)d_in[5];
  const float* b2  = (const float*)d_in[6];

  float* I0T = (float*)d_ws;                 // 6.55 MB, b-major [b][t][j]
  short* W0s = (short*)(I0T + I0ELEMS);      // 3 x 100 KB bf16 splits

  prep_w0<<<dim3(200), dim3(256), 0, stream>>>(W0, W0s);
  gemm0_kernel<<<dim3(1600), dim3(256), 0, stream>>>(inp, W0s, b0, I0T);
  fused_kernel<<<dim3(BATCH), dim3(256), 0, stream>>>(I0T, W1, b1, W2, b2,
                                                      (float*)d_out);
}

// Round 12
// 65.254 us; speedup vs baseline: 1.1463x; 1.1463x over previous
//
#include <hip/hip_runtime.h>

#define T_STEPS 100
#define BATCH 256
#define NIN 784
#define N0 64
#define N1 64
#define N2 10
#define CHUNK (BATCH*N0 + BATCH*N1 + BATCH*N2)   // 35328
#define KPAD 800
#define NCH 25                                   // packed 32-k chunks (800/32)
#define I0ELEMS (25600*64)
#define AROW 40                                  // shorts per LDS A-row (80B, 16B-aligned)
#define ASPL (32*AROW)                           // shorts per split plane (per wave)
#define AWAVE (3*ASPL)                           // shorts per wave A-buffer (7680B)

typedef __attribute__((ext_vector_type(8))) short short8;
typedef __attribute__((ext_vector_type(4))) short short4v;
typedef __attribute__((ext_vector_type(4))) float f32x4;

__device__ inline short bf16_rne(float x) {
  unsigned u = __float_as_uint(x);
  unsigned h = (u + 0x7FFFu + ((u >> 16) & 1u)) >> 16;
  return (short)h;
}
__device__ inline float bf16_val(short h) {
  return __uint_as_float(((unsigned)(unsigned short)h) << 16);
}

// ---------------------------------------------------------------------------
// Kernel 0: pack W0 (f32 [64][784]) into bf16x3 FRAGMENT-COALESCED layout:
// W0p[c][p][ct][lane][e] (short), c=chunk of 32 k, lane = MFMA B-frag lane,
// so gemm's B loads are lane-consecutive (fully coalesced). Zero-pad k>=784.
// ---------------------------------------------------------------------------
__global__ __launch_bounds__(256) void prep_w0_pack(
    const float* __restrict__ W0, short* __restrict__ W0p) {
  int idx = blockIdx.x * 256 + threadIdx.x;      // 0..153599
  int e  = idx & 7;
  int r1 = idx >> 3;
  int l  = r1 & 63;
  int r2 = r1 >> 6;
  int ct = r2 & 3;
  int r3 = r2 >> 2;
  int p  = r3 % 3;
  int c  = r3 / 3;                               // 0..24
  int k   = c * 32 + (l >> 4) * 8 + e;
  int col = ct * 16 + (l & 15);
  float w = (k < NIN) ? W0[col * NIN + k] : 0.0f;
  short h0 = bf16_rne(w);
  float rr1 = w - bf16_val(h0);
  short h1 = bf16_rne(rr1);
  float rr2 = rr1 - bf16_val(h1);
  short h2 = bf16_rne(rr2);
  W0p[idx] = (p == 0) ? h0 : (p == 1) ? h1 : h2;
}

// ---------------------------------------------------------------------------
// Kernel 1: I0T = X @ W0^T + b0 via bf16x3 MFMA.
// Block = 32 rows x 64 cols, 4 waves = 4 k-ranges {192,192,192,224-pad}
// (bit-identical FP chains to R10/R11). NO barriers in the k-loop:
//  - B: direct from packed W0p, fully coalesced 1KB loads.
//  - A: coalesced global float4 -> in-reg bf16x3 convert -> wave-private LDS
//    -> ds_read_b128 fragments (same-wave DS ops are in-order).
// Epilogue: one barrier, LDS reduce of 4 wave-partials (+bias), b-major I0T.
// ---------------------------------------------------------------------------
__global__ __launch_bounds__(256) void gemm0_kernel(
    const float* __restrict__ X, const short* __restrict__ W0p,
    const float* __restrict__ b0, float* __restrict__ I0T) {
  __shared__ __align__(16) char smem[4 * 32 * 68 * 4];   // 34816 B
  // per-wave A buffers (30720 B) alias the low part; red overlays after sync
  const int tid = threadIdx.x;
  const int r0  = blockIdx.x * 32;
  const int wid = tid >> 6;                      // wave = k-split
  const int l   = tid & 63;
  const int lr  = l & 15;
  const int lk  = l >> 4;

  short* Aw = (short*)smem + wid * AWAVE;
  float (*red)[32][68] = (float(*)[32][68])smem;

  const int kbeg = wid * 192;
  const int ccnt = (wid < 3) ? 6 : 7;
  const int gbase = kbeg >> 5;                   // global chunk base (wid*6)

  f32x4 acc[2][4];
#pragma unroll
  for (int rt = 0; rt < 2; ++rt)
#pragma unroll
    for (int ct = 0; ct < 4; ++ct) acc[rt][ct] = f32x4{0.f, 0.f, 0.f, 0.f};

  const short8* wp8 = (const short8*)W0p;
  const float4  z4  = {0.f, 0.f, 0.f, 0.f};

  // A staging maps: f = i*64 + l -> row = f>>3 (0..31), kseg = f&7 (4 floats)
  const int srow0 = l >> 3;                      // + i*8
  const int sks   = l & 7;

  // ---- stage helper (macro-ish via lambda, unrolled)
  auto A_LOAD = [&](int kb, float4 xa[4]) {
#pragma unroll
    for (int i = 0; i < 4; ++i) {
      int row = srow0 + i * 8;
      int k   = kb + sks * 4;
      xa[i] = (k < NIN) ? *(const float4*)(X + (size_t)(r0 + row) * NIN + k) : z4;
    }
  };
  auto A_WRITE = [&](float4 xa[4]) {
#pragma unroll
    for (int i = 0; i < 4; ++i) {
      int row = srow0 + i * 8;
      float xs[4] = {xa[i].x, xa[i].y, xa[i].z, xa[i].w};
      short4v v0, v1, v2;
#pragma unroll
      for (int e = 0; e < 4; ++e) {
        float x  = xs[e];
        short h0 = bf16_rne(x);   float rr1 = x - bf16_val(h0);
        short h1 = bf16_rne(rr1); float rr2 = rr1 - bf16_val(h1);
        v0[e] = h0; v1[e] = h1; v2[e] = bf16_rne(rr2);
      }
      short* base = Aw + row * AROW + sks * 4;
      *(short4v*)(base)            = v0;
      *(short4v*)(base + ASPL)     = v1;
      *(short4v*)(base + 2 * ASPL) = v2;
    }
  };

  // ---- prologue: stage chunk 0
  {
    float4 xa[4];
    A_LOAD(kbeg, xa);
    A_WRITE(xa);
  }

  for (int c = 0; c < ccnt; ++c) {
    const bool more = (c + 1 < ccnt);
    const int g = gbase + c;

    // ---- B loads: 12 coalesced 1KB loads from packed layout
    short8 cb[4][3];
#pragma unroll
    for (int ct = 0; ct < 4; ++ct) {
#pragma unroll
      for (int p = 0; p < 3; ++p)
        cb[ct][p] = wp8[(size_t)(((g * 3 + p) * 4 + ct)) * 64 + l];
    }

    // ---- A global prefetch for next chunk (HBM latency hides under MFMAs)
    float4 xn[4];
    if (more) A_LOAD(kbeg + (c + 1) * 32, xn);

    // ---- A fragment reads from wave-private LDS (in-order vs prior writes)
    short8 af[2][3];
#pragma unroll
    for (int rti = 0; rti < 2; ++rti)
#pragma unroll
      for (int p = 0; p < 3; ++p)
        af[rti][p] = *(const short8*)(Aw + p * ASPL + (rti * 16 + lr) * AROW + lk * 8);

    // ---- MFMA: 2 row-tiles x 4 col-tiles x 6 products (R10 order)
#pragma unroll
    for (int ct = 0; ct < 4; ++ct) {
      {
        f32x4 a = acc[0][ct];
        a = __builtin_amdgcn_mfma_f32_16x16x32_bf16(af[0][2], cb[ct][0], a, 0, 0, 0);
        a = __builtin_amdgcn_mfma_f32_16x16x32_bf16(af[0][0], cb[ct][2], a, 0, 0, 0);
        a = __builtin_amdgcn_mfma_f32_16x16x32_bf16(af[0][1], cb[ct][1], a, 0, 0, 0);
        a = __builtin_amdgcn_mfma_f32_16x16x32_bf16(af[0][1], cb[ct][0], a, 0, 0, 0);
        a = __builtin_amdgcn_mfma_f32_16x16x32_bf16(af[0][0], cb[ct][1], a, 0, 0, 0);
        a = __builtin_amdgcn_mfma_f32_16x16x32_bf16(af[0][0], cb[ct][0], a, 0, 0, 0);
        acc[0][ct] = a;
      }
      {
        f32x4 a = acc[1][ct];
        a = __builtin_amdgcn_mfma_f32_16x16x32_bf16(af[1][2], cb[ct][0], a, 0, 0, 0);
        a = __builtin_amdgcn_mfma_f32_16x16x32_bf16(af[1][0], cb[ct][2], a, 0, 0, 0);
        a = __builtin_amdgcn_mfma_f32_16x16x32_bf16(af[1][1], cb[ct][1], a, 0, 0, 0);
        a = __builtin_amdgcn_mfma_f32_16x16x32_bf16(af[1][1], cb[ct][0], a, 0, 0, 0);
        a = __builtin_amdgcn_mfma_f32_16x16x32_bf16(af[1][0], cb[ct][1], a, 0, 0, 0);
        a = __builtin_amdgcn_mfma_f32_16x16x32_bf16(af[1][0], cb[ct][0], a, 0, 0, 0);
        acc[1][ct] = a;
      }
    }

    // ---- convert + write next chunk's A (DS in-order: after this chunk's reads)
    if (more) A_WRITE(xn);
  }

  // ---- all waves done with A buffers before red overlays them
  __syncthreads();

  // C/D map: col = l&15, row = (l>>4)*4 + r
#pragma unroll
  for (int rt = 0; rt < 2; ++rt)
#pragma unroll
    for (int ct = 0; ct < 4; ++ct)
#pragma unroll
      for (int r = 0; r < 4; ++r)
        red[wid][rt * 16 + lk * 4 + r][ct * 16 + lr] = acc[rt][ct][r];
  __syncthreads();

  // ---- reduce 4 partials + bias (R10 order), write b-major I0T
  const int t0  = r0 >> 8;
  const int bb0 = r0 & 255;
  for (int idx = tid; idx < 32 * 16; idx += 256) {
    int row = idx >> 4, q = idx & 15;
    float4 v  = *(const float4*)&red[0][row][q * 4];
    float4 u1 = *(const float4*)&red[1][row][q * 4];
    float4 u2 = *(const float4*)&red[2][row][q * 4];
    float4 u3 = *(const float4*)&red[3][row][q * 4];
    v.x += u1.x; v.y += u1.y; v.z += u1.z; v.w += u1.w;
    v.x += u2.x; v.y += u2.y; v.z += u2.z; v.w += u2.w;
    v.x += u3.x; v.y += u3.y; v.z += u3.z; v.w += u3.w;
    float4 bv = ((const float4*)b0)[q];
    v.x += bv.x; v.y += bv.y; v.z += bv.z; v.w += bv.w;
    ((float4*)I0T)[((size_t)(bb0 + row) * T_STEPS + t0) * 16 + q] = v;
  }
}

// ---------------------------------------------------------------------------
// Kernel 2: one block per batch element (unchanged).
// ---------------------------------------------------------------------------
__global__ __launch_bounds__(256) void fused_kernel(
    const float* __restrict__ I0T,
    const float* __restrict__ W1, const float* __restrict__ b1,
    const float* __restrict__ W2, const float* __restrict__ b2,
    float* __restrict__ out) {
  __shared__ float bufA[112][68];
  __shared__ float sW1t[64][68];
  __shared__ float sW2[N2][68];
  __shared__ float sI2[T_STEPS][N2];

  const int b   = blockIdx.x;
  const int tid = threadIdx.x;
  const int j   = tid & 63;
  const int tq  = tid >> 6;
  float* outSpk = out;
  float* laySpk = out + T_STEPS * BATCH * N2;

  {
    const float4* src = (const float4*)I0T + (size_t)b * (T_STEPS * 16);
    for (int idx = tid; idx < T_STEPS * 16; idx += 256) {
      float4 v = src[idx];
      int t = idx >> 4, j4 = idx & 15;
      *(float4*)&bufA[t][j4 * 4] = v;
    }
  }
  __syncthreads();

  if (tq == 0) {
    float v = 0.0f;
#pragma unroll
    for (int g = 0; g < 4; ++g) {
      float ic[25];
#pragma unroll
      for (int i = 0; i < 25; ++i) ic[i] = bufA[g * 25 + i][j];
#pragma unroll
      for (int i = 0; i < 25; ++i) {
        v = v + 0.05f * ((0.0f - v) + ic[i]);
        float z = (v > 1.0f) ? 1.0f : 0.0f;
        v -= z;
        ic[i] = z;
      }
#pragma unroll
      for (int i = 0; i < 25; ++i) bufA[g * 25 + i][j] = ic[i];
    }
  } else {
    for (int idx = tid - 64; idx < 64 * 16; idx += 192) {
      int i = idx >> 4, jv = idx & 15;
      float4 wv = *(const float4*)(W1 + (size_t)i * 64 + jv * 4);
      sW1t[jv * 4 + 0][i] = wv.x;
      sW1t[jv * 4 + 1][i] = wv.y;
      sW1t[jv * 4 + 2][i] = wv.z;
      sW1t[jv * 4 + 3][i] = wv.w;
    }
    for (int idx = tid - 64; idx < N2 * 16; idx += 192) {
      int o = idx >> 4, jv = idx & 15;
      *(float4*)&sW2[o][jv * 4] = *(const float4*)(W2 + (size_t)o * 64 + jv * 4);
    }
  }
  __syncthreads();

  for (int idx = tid; idx < T_STEPS * 16; idx += 256) {
    int t = idx >> 4, jv = idx & 15;
    *(float4*)(laySpk + (size_t)t * CHUNK + b * 64 + jv * 4) =
        *(const float4*)&bufA[t][jv * 4];
  }

  const int iq = tid & 15;
  const int ts = tid >> 4;
  float g1[4][7];
  {
    float4 bias = *(const float4*)(b1 + iq * 4);
#pragma unroll
    for (int tt = 0; tt < 7; ++tt) {
      g1[0][tt] = bias.x; g1[1][tt] = bias.y; g1[2][tt] = bias.z; g1[3][tt] = bias.w;
    }
#pragma unroll
    for (int jq = 0; jq < 16; ++jq) {
      float4 z4[7];
#pragma unroll
      for (int tt = 0; tt < 7; ++tt)
        z4[tt] = *(const float4*)&bufA[ts * 7 + tt][jq * 4];
      float4 w4[4];
#pragma unroll
      for (int e = 0; e < 4; ++e)
        w4[e] = *(const float4*)&sW1t[jq * 4 + e][iq * 4];
#pragma unroll
      for (int e = 0; e < 4; ++e) {
#pragma unroll
        for (int tt = 0; tt < 7; ++tt) {
          float zv = ((const float*)&z4[tt])[e];
          g1[0][tt] = fmaf(zv, w4[e].x, g1[0][tt]);
          g1[1][tt] = fmaf(zv, w4[e].y, g1[1][tt]);
          g1[2][tt] = fmaf(zv, w4[e].z, g1[2][tt]);
          g1[3][tt] = fmaf(zv, w4[e].w, g1[3][tt]);
        }
      }
    }
  }
  __syncthreads();
#pragma unroll
  for (int tt = 0; tt < 7; ++tt) {
    float4 o = {g1[0][tt], g1[1][tt], g1[2][tt], g1[3][tt]};
    *(float4*)&bufA[ts * 7 + tt][iq * 4] = o;
  }
  __syncthreads();

  if (tq == 0) {
    float v = 0.0f;
#pragma unroll
    for (int g = 0; g < 4; ++g) {
      float ic[25];
#pragma unroll
      for (int i = 0; i < 25; ++i) ic[i] = bufA[g * 25 + i][j];
#pragma unroll
      for (int i = 0; i < 25; ++i) {
        v = v + 0.05f * ((0.0f - v) + ic[i]);
        float z = (v > 1.0f) ? 1.0f : 0.0f;
        v -= z;
        ic[i] = z;
      }
#pragma unroll
      for (int i = 0; i < 25; ++i) bufA[g * 25 + i][j] = ic[i];
    }
  }
  __syncthreads();

  for (int idx = tid; idx < T_STEPS * 16; idx += 256) {
    int t = idx >> 4, jv = idx & 15;
    *(float4*)(laySpk + (size_t)t * CHUNK + BATCH * N0 + b * 64 + jv * 4) =
        *(const float4*)&bufA[t][jv * 4];
  }

  for (int idx = tid; idx < T_STEPS * N2; idx += 256) {
    int t = idx / N2, o = idx % N2;
    float a = b2[o];
#pragma unroll
    for (int jq = 0; jq < 16; ++jq) {
      float4 z = *(const float4*)&bufA[t][jq * 4];
      float4 wv = *(const float4*)&sW2[o][jq * 4];
      a += z.x * wv.x;
      a += z.y * wv.y;
      a += z.z * wv.z;
      a += z.w * wv.w;
    }
    sI2[t][o] = a;
  }
  __syncthreads();

  if (tid < N2) {
    float v = 0.0f;
#pragma unroll
    for (int g = 0; g < 4; ++g) {
      float ic[25];
#pragma unroll
      for (int i = 0; i < 25; ++i) ic[i] = sI2[g * 25 + i][tid];
#pragma unroll
      for (int i = 0; i < 25; ++i) {
        v = v + 0.05f * ((0.0f - v) + ic[i]);
        float z = (v > 1.0f) ? 1.0f : 0.0f;
        v -= z;
        ic[i] = z;
      }
#pragma unroll
      for (int i = 0; i < 25; ++i) sI2[g * 25 + i][tid] = ic[i];
    }
  }
  __syncthreads();

  for (int idx = tid; idx < T_STEPS * N2; idx += 256) {
    int t = idx / N2, o = idx % N2;
    float z = sI2[t][o];
    outSpk[(size_t)t * (BATCH * N2) + b * N2 + o] = z;
    laySpk[(size_t)t * CHUNK + BATCH * (N0 + N1) + b * N2 + o] = z;
  }
}

extern "C" void kernel_launch(void* const* d_in, const int* in_sizes, int n_in,
                              void* d_out, int out_size, void* d_ws, size_t ws_size,
                              hipStream_t stream) {
  const float* inp = (const float*)d_in[0];
  const float* W0  = (const float*)d_in[1];
  const float* b0  = (const float*)d_in[2];
  const float* W1  = (const float*)d_in[3];
  const float* b1  = (const float*)d_in[4];
  const float* W2  = (const float*)d_in[5];
  const float* b2  = (const float*)d_in[6];

  float* I0T = (float*)d_ws;                 // 6.55 MB, b-major [b][t][j]
  short* W0p = (short*)(I0T + I0ELEMS);      // 300 KB packed bf16x3 fragments

  prep_w0_pack<<<dim3(600), dim3(256), 0, stream>>>(W0, W0p);
  gemm0_kernel<<<dim3(800), dim3(256), 0, stream>>>(inp, W0p, b0, I0T);
  fused_kernel<<<dim3(BATCH), dim3(256), 0, stream>>>(I0T, W1, b1, W2, b2,
                                                      (float*)d_out);
}